// Round 2
// baseline (258.659 us; speedup 1.0000x reference)
//
#include <hip/hip_runtime.h>
#include <math.h>

#define BATCH 32
#define HW 16384
#define WIDTH 128
#define NLINES 1000
#define NCAND 4096

// Flat output offsets (float elements), in reference return order:
// lcmap (32,128,128), lcoff (32,2,128,128), lleng (32,128,128),
// angle (32,128,128), lines (32,1000,2,2), score (32,1000)
#define OFF_LCMAP 0
#define OFF_LCOFF (BATCH * HW)                       // 524288
#define OFF_LLENG (OFF_LCOFF + 2 * BATCH * HW)       // 1572864
#define OFF_ANGLE (OFF_LLENG + BATCH * HW)           // 2097152
#define OFF_LINES (OFF_ANGLE + BATCH * HW)           // 2621440
#define OFF_SCORE (OFF_LINES + BATCH * NLINES * 4)   // 2749440

// Workspace layout: [32 x int cnt][pad to 128B][32*4096 x u64 keys]
#define WS_KEYS_OFF 128                               // bytes
#define WS_NEEDED (WS_KEYS_OFF + (size_t)BATCH * NCAND * 8)

__device__ __forceinline__ float sigmoidf_(float x) {
    return 1.0f / (1.0f + expf(-x));
}

// Elementwise transforms; also zeroes the workspace counters + key slots.
__global__ void prep_kernel(const float* __restrict__ in, float* __restrict__ out,
                            unsigned long long* __restrict__ wskeys,
                            int* __restrict__ wscnt, int do_ws) {
    int tid = blockIdx.x * blockDim.x + threadIdx.x;
    if (do_ws) {
        if (tid < BATCH * NCAND) wskeys[tid] = 0ULL;
        if (tid < BATCH) wscnt[tid] = 0;
    }
    if (tid >= BATCH * HW) return;
    int b = tid >> 14;          // / 16384
    int p = tid & (HW - 1);
    const float* ib = in + (size_t)b * 6 * HW;
    float x0 = ib[p];
    float x1 = ib[HW + p];
    float x2 = ib[2 * HW + p];
    float x3 = ib[3 * HW + p];
    float x4 = ib[4 * HW + p];
    float x5 = ib[5 * HW + p];
    float m = fmaxf(x0, x1);
    float e0 = expf(x0 - m);
    float e1 = expf(x1 - m);
    out[OFF_LCMAP + tid] = e1 / (e0 + e1);
    out[OFF_LCOFF + b * 2 * HW + p]      = sigmoidf_(x2) - 0.5f;
    out[OFF_LCOFF + b * 2 * HW + HW + p] = sigmoidf_(x3) - 0.5f;
    out[OFF_LLENG + tid] = sigmoidf_(x4);
    out[OFF_ANGLE + tid] = sigmoidf_(x5);
}

// Branchless local-max test: all 8 neighbor loads issue independently (clamped
// address + in-bounds select), no serializing early-returns.
__device__ __forceinline__ bool keep_branchless(const float* __restrict__ L, int p) {
    int y = p >> 7, x = p & (WIDTH - 1);
    float v = L[p];
    float m = -INFINITY;
    #pragma unroll
    for (int dy = -1; dy <= 1; ++dy) {
        #pragma unroll
        for (int dx = -1; dx <= 1; ++dx) {
            if (dy == 0 && dx == 0) continue;
            int yy = y + dy, xx = x + dx;
            int yc = min(max(yy, 0), WIDTH - 1);
            int xc = min(max(xx, 0), WIDTH - 1);
            float nv = L[yc * WIDTH + xc];
            bool inb = ((unsigned)yy < (unsigned)WIDTH) & ((unsigned)xx < (unsigned)WIDTH);
            m = fmaxf(m, inb ? nv : -INFINITY);
        }
    }
    return v >= m;
}

__device__ __forceinline__ unsigned long long pack_key(float v, unsigned p) {
    // value strictly > 0 -> float bits order == value order; inverted index
    // gives lower-index-first on value ties (replicates stable lax.top_k).
    return ((unsigned long long)__float_as_uint(v) << 32)
         | (unsigned long long)(0xFFFFFFFFu - p);
}

// Full-GPU candidate collection into workspace (wave-aggregated atomics).
__global__ void collect_kernel(const float* __restrict__ out,
                               unsigned long long* __restrict__ wskeys,
                               int* __restrict__ wscnt) {
    int tid = blockIdx.x * blockDim.x + threadIdx.x;   // one pixel per thread
    int b = tid >> 14;
    int p = tid & (HW - 1);
    const float* __restrict__ L = out + OFF_LCMAP + b * HW;
    float v = L[p];
    bool keep = keep_branchless(L, p);
    unsigned long long mask = __ballot(keep);
    int lane = threadIdx.x & 63;
    int base = 0;
    if (lane == 0 && mask) base = atomicAdd(&wscnt[b], __popcll(mask));
    base = __shfl(base, 0);
    if (keep) {
        int pos = base + __popcll(mask & ((1ULL << lane) - 1ULL));
        if (pos < NCAND)
            wskeys[b * NCAND + pos] = pack_key(v, (unsigned)p);
    }
}

// Serial-safe fallback keep (only used on the never-hit cnt<NLINES path).
__device__ __forceinline__ bool is_keep_serial(const float* __restrict__ L, int p) {
    return keep_branchless(L, p);
}

// One block per batch: (optionally collect) -> bitonic sort -> lines -> NMS.
template <bool USE_WS>
__global__ __launch_bounds__(1024) void finalize_kernel(
        float* __restrict__ out,
        const unsigned long long* __restrict__ wskeys,
        const int* __restrict__ wscnt) {
    __shared__ unsigned long long keys[NCAND];   // 32 KB
    __shared__ float ls[NLINES * 4];             // 16 KB
    __shared__ float ss[NLINES];                 //  4 KB
    __shared__ int cnt;

    const int b = blockIdx.x;
    const int tid = threadIdx.x;
    const float* __restrict__ L = out + OFF_LCMAP + b * HW;

    if (USE_WS) {
        for (int i = tid; i < NCAND; i += 1024) keys[i] = wskeys[b * NCAND + i];
        if (tid == 0) cnt = wscnt[b];
    } else {
        if (tid == 0) cnt = 0;
        for (int i = tid; i < NCAND; i += 1024) keys[i] = 0ULL;
        __syncthreads();
        for (int p = tid; p < HW; p += 1024) {
            float v = L[p];
            bool keep = keep_branchless(L, p);
            unsigned long long mask = __ballot(keep);
            int lane = tid & 63;
            int base = 0;
            if (lane == 0 && mask) base = atomicAdd(&cnt, __popcll(mask));
            base = __shfl(base, 0);
            if (keep) {
                int pos = base + __popcll(mask & ((1ULL << lane) - 1ULL));
                if (pos < NCAND) keys[pos] = pack_key(v, (unsigned)p);
            }
        }
    }
    __syncthreads();

    // Bitonic sort, descending (keys unique -> total order).
    for (int size = 2; size <= NCAND; size <<= 1) {
        for (int stride = size >> 1; stride > 0; stride >>= 1) {
            for (int idx = tid; idx < NCAND; idx += 1024) {
                int partner = idx ^ stride;
                if (partner > idx) {
                    bool up = ((idx & size) != 0);
                    unsigned long long a = keys[idx];
                    unsigned long long c = keys[partner];
                    if ((a > c) == up) { keys[idx] = c; keys[partner] = a; }
                }
            }
            __syncthreads();
        }
    }

    // Fallback (never triggers for this seed): top_k pads with zeros at the
    // lowest non-kept flat indices.
    if (tid == 0 && cnt < NLINES) {
        int c = cnt < NCAND ? cnt : NCAND;
        int need = NLINES - c;
        int filled = 0;
        for (int p = 0; p < HW && filled < need; ++p) {
            if (!is_keep_serial(L, p)) {
                keys[c + filled] = (unsigned long long)(0xFFFFFFFFu - (unsigned)p);
                ++filled;
            }
        }
    }
    __syncthreads();

    // Line endpoints for the top NLINES.
    const float* __restrict__ off0 = out + OFF_LCOFF + b * 2 * HW;
    const float* __restrict__ off1 = off0 + HW;
    const float* __restrict__ leng = out + OFF_LLENG + b * HW;
    const float* __restrict__ ang  = out + OFF_ANGLE + b * HW;
    for (int k = tid; k < NLINES; k += 1024) {
        unsigned long long key = keys[k];
        unsigned p = 0xFFFFFFFFu - (unsigned)(key & 0xFFFFFFFFull);
        float score = __uint_as_float((unsigned)(key >> 32));
        int yi = p >> 7, xi = p & (WIDTH - 1);
        float yc = (float)yi + off0[p] + 0.5f;
        float xc = (float)xi + off1[p] + 0.5f;
        float half_len = leng[p] * 64.0f;            // RESOLUTION/2
        float th = ang[p] * 3.14159265358979323846f;
        float dy = half_len * sinf(th);
        float dx = half_len * cosf(th);
        float p1y = yc - dy, p1x = xc - dx;
        float p2y = yc + dy, p2x = xc + dx;
        float* lo = out + OFF_LINES + (size_t)(b * NLINES + k) * 4;
        lo[0] = p1y; lo[1] = p1x; lo[2] = p2y; lo[3] = p2x;
        ls[k * 4 + 0] = p1y; ls[k * 4 + 1] = p1x;
        ls[k * 4 + 2] = p2y; ls[k * 4 + 3] = p2x;
        ss[k] = score;
    }
    __syncthreads();

    // Structure NMS: suppress k if any i<k has min-pairing sq-dist <= 2.0.
    for (int k = tid; k < NLINES; k += 1024) {
        float p1y = ls[k * 4 + 0], p1x = ls[k * 4 + 1];
        float p2y = ls[k * 4 + 2], p2x = ls[k * 4 + 3];
        bool sup = false;
        for (int i = 0; i < k; ++i) {
            float q1y = ls[i * 4 + 0], q1x = ls[i * 4 + 1];
            float q2y = ls[i * 4 + 2], q2x = ls[i * 4 + 3];
            float d1 = (q1y - p1y) * (q1y - p1y) + (q1x - p1x) * (q1x - p1x)
                     + (q2y - p2y) * (q2y - p2y) + (q2x - p2x) * (q2x - p2x);
            float d2 = (q1y - p2y) * (q1y - p2y) + (q1x - p2x) * (q1x - p2x)
                     + (q2y - p1y) * (q2y - p1y) + (q2x - p1x) * (q2x - p1x);
            if (fminf(d1, d2) <= 2.0f) { sup = true; break; }
        }
        out[OFF_SCORE + b * NLINES + k] = sup ? 0.0f : ss[k];
    }
}

extern "C" void kernel_launch(void* const* d_in, const int* in_sizes, int n_in,
                              void* d_out, int out_size, void* d_ws, size_t ws_size,
                              hipStream_t stream) {
    const float* in = (const float*)d_in[0];
    float* out = (float*)d_out;
    (void)in_sizes; (void)n_in; (void)out_size;

    const bool use_ws = (d_ws != nullptr) && (ws_size >= WS_NEEDED);
    int* wscnt = (int*)d_ws;
    unsigned long long* wskeys =
        (unsigned long long*)((char*)d_ws + WS_KEYS_OFF);

    prep_kernel<<<(BATCH * HW + 255) / 256, 256, 0, stream>>>(
        in, out, wskeys, wscnt, use_ws ? 1 : 0);

    if (use_ws) {
        collect_kernel<<<(BATCH * HW) / 256, 256, 0, stream>>>(out, wskeys, wscnt);
        finalize_kernel<true><<<BATCH, 1024, 0, stream>>>(out, wskeys, wscnt);
    } else {
        finalize_kernel<false><<<BATCH, 1024, 0, stream>>>(out, nullptr, nullptr);
    }
}

// Round 3
// 137.348 us; speedup vs baseline: 1.8832x; 1.8832x over previous
//
#include <hip/hip_runtime.h>
#include <math.h>

#define BATCH 32
#define HW 16384
#define WIDTH 128
#define NLINES 1000
#define NCAND 4096
#define CHUNK 1024
#define NCHUNK 4

// Flat output offsets (float elements), reference return order:
// lcmap (32,128,128), lcoff (32,2,128,128), lleng (32,128,128),
// angle (32,128,128), lines (32,1000,2,2), score (32,1000)
#define OFF_LCMAP 0
#define OFF_LCOFF (BATCH * HW)
#define OFF_LLENG (OFF_LCOFF + 2 * BATCH * HW)
#define OFF_ANGLE (OFF_LLENG + BATCH * HW)
#define OFF_LINES (OFF_ANGLE + BATCH * HW)
#define OFF_SCORE (OFF_LINES + BATCH * NLINES * 4)

// Workspace: [32 int cnt][pad to 128B][32*4096 u64 keys]
#define WS_KEYS_OFF 128
#define WS_NEEDED (WS_KEYS_OFF + (size_t)BATCH * NCAND * 8)

#define PI_F 3.14159265358979323846f

__device__ __forceinline__ float sigmoidf_(float x) {
    return 1.0f / (1.0f + expf(-x));
}

// Exactly the reference softmax([x0,x1])[1] op sequence -> bit-identical.
__device__ __forceinline__ float softmax1(float x0, float x1) {
    float m = fmaxf(x0, x1);
    float e0 = expf(x0 - m);
    float e1 = expf(x1 - m);
    return e1 / (e0 + e1);
}

__device__ __forceinline__ unsigned long long pack_key(float v, unsigned p) {
    // v > 0 -> float-bit order == value order; inverted index replicates
    // stable lax.top_k tie-breaking (lower index first).
    return ((unsigned long long)__float_as_uint(v) << 32)
         | (unsigned long long)(0xFFFFFFFFu - p);
}

// K0: zero the 32 per-batch counters (tiny).
__global__ void zero_cnt_kernel(int* __restrict__ wscnt) {
    if (threadIdx.x < BATCH) wscnt[threadIdx.x] = 0;
}

// K1: elementwise transforms + fused local-max candidate collection.
// Neighbor lcmap recomputed from input (bit-identical to stored values).
__global__ __launch_bounds__(256) void prep_collect_kernel(
        const float* __restrict__ in, float* __restrict__ out,
        unsigned long long* __restrict__ wskeys, int* __restrict__ wscnt) {
    int tid = blockIdx.x * 256 + threadIdx.x;
    int b = tid >> 14;              // HW = 16384
    int p = tid & (HW - 1);
    const float* __restrict__ ib = in + (size_t)b * 6 * HW;

    float x0 = ib[p];
    float x1 = ib[HW + p];
    float x2 = ib[2 * HW + p];
    float x3 = ib[3 * HW + p];
    float x4 = ib[4 * HW + p];
    float x5 = ib[5 * HW + p];

    float v = softmax1(x0, x1);
    out[OFF_LCMAP + tid] = v;
    out[OFF_LCOFF + b * 2 * HW + p]      = sigmoidf_(x2) - 0.5f;
    out[OFF_LCOFF + b * 2 * HW + HW + p] = sigmoidf_(x3) - 0.5f;
    out[OFF_LLENG + tid] = sigmoidf_(x4);
    out[OFF_ANGLE + tid] = sigmoidf_(x5);

    // 3x3 local-max test vs in-bounds neighbors (== h == maxpool3x3(h)).
    int y = p >> 7, x = p & (WIDTH - 1);
    float m = -INFINITY;
    #pragma unroll
    for (int dy = -1; dy <= 1; ++dy) {
        #pragma unroll
        for (int dx = -1; dx <= 1; ++dx) {
            if (dy == 0 && dx == 0) continue;
            int yy = y + dy, xx = x + dx;
            int yc = min(max(yy, 0), WIDTH - 1);
            int xc = min(max(xx, 0), WIDTH - 1);
            int np = yc * WIDTH + xc;
            float nv = softmax1(ib[np], ib[HW + np]);
            bool inb = ((unsigned)yy < (unsigned)WIDTH) & ((unsigned)xx < (unsigned)WIDTH);
            m = fmaxf(m, inb ? nv : -INFINITY);
        }
    }
    bool keep = (v >= m);

    unsigned long long mask = __ballot(keep);
    int lane = threadIdx.x & 63;
    int base = 0;
    if (lane == 0 && mask) base = atomicAdd(&wscnt[b], __popcll(mask));
    base = __shfl(base, 0);
    if (keep) {
        int pos = base + __popcll(mask & ((1ULL << lane) - 1ULL));
        if (pos < NCAND)
            wskeys[(size_t)b * NCAND + pos] = pack_key(v, (unsigned)p);
    }
}

// K2: per-(batch,chunk) bitonic sort of 1024 keys, descending; slots >= cnt
// read as 0 and written back (materializes the zero padding).
__global__ __launch_bounds__(512) void sort_chunks_kernel(
        unsigned long long* __restrict__ wskeys, const int* __restrict__ wscnt) {
    __shared__ unsigned long long sk[CHUNK];
    const int c = blockIdx.x, b = blockIdx.y;
    int cnt = wscnt[b]; if (cnt > NCAND) cnt = NCAND;
    const int base = c * CHUNK;
    unsigned long long* gk = wskeys + (size_t)b * NCAND;

    for (int i = threadIdx.x; i < CHUNK; i += 512)
        sk[i] = (base + i < cnt) ? gk[base + i] : 0ULL;
    __syncthreads();

    for (int size = 2; size <= CHUNK; size <<= 1) {
        for (int stride = size >> 1; stride > 0; stride >>= 1) {
            int t = threadIdx.x;
            int i = ((t & ~(stride - 1)) << 1) | (t & (stride - 1));
            int j = i | stride;
            bool asc = (i & size) != 0;
            unsigned long long a = sk[i], cc = sk[j];
            if ((a < cc) != asc) { sk[i] = cc; sk[j] = a; }
            __syncthreads();
        }
    }
    for (int i = threadIdx.x; i < CHUNK; i += 512)
        gk[base + i] = sk[i];
}

// K3: merge 4 sorted chunks by exact rank (binary search; keys unique),
// compute line endpoints + raw scores for ranks < 1000.
__global__ __launch_bounds__(1024) void merge_lines_kernel(
        float* __restrict__ out, const unsigned long long* __restrict__ wskeys) {
    __shared__ unsigned long long sk[NCAND];   // 32 KB
    const int b = blockIdx.x;
    const unsigned long long* gk = wskeys + (size_t)b * NCAND;
    for (int i = threadIdx.x; i < NCAND; i += 1024) sk[i] = gk[i];
    __syncthreads();

    const float* off0 = out + OFF_LCOFF + b * 2 * HW;
    const float* off1 = off0 + HW;
    const float* leng = out + OFF_LLENG + b * HW;
    const float* ang  = out + OFF_ANGLE + b * HW;

    for (int mslot = threadIdx.x; mslot < NCAND; mslot += 1024) {
        unsigned long long e = sk[mslot];
        if (e == 0ULL) continue;                 // zero pad: rank >= cnt
        int c = mslot >> 10;
        int rank = mslot & (CHUNK - 1);          // local rank in own chunk
        #pragma unroll
        for (int c2 = 0; c2 < NCHUNK; ++c2) {
            if (c2 == c) continue;
            const unsigned long long* A = sk + c2 * CHUNK;
            int lo = 0, hi = CHUNK;
            while (lo < hi) {
                int mid = (lo + hi) >> 1;
                if (A[mid] > e) lo = mid + 1; else hi = mid;
            }
            rank += lo;                          // count of keys > e in c2
        }
        if (rank < NLINES) {
            unsigned p = 0xFFFFFFFFu - (unsigned)(e & 0xFFFFFFFFull);
            float score = __uint_as_float((unsigned)(e >> 32));
            int yi = (int)(p >> 7), xi = (int)(p & (WIDTH - 1));
            float yc = (float)yi + off0[p] + 0.5f;
            float xc = (float)xi + off1[p] + 0.5f;
            float hl = leng[p] * 64.0f;          // RESOLUTION/2
            float th = ang[p] * PI_F;
            float dy = hl * sinf(th);
            float dx = hl * cosf(th);
            float4 ln = make_float4(yc - dy, xc - dx, yc + dy, xc + dx);
            *(float4*)(out + OFF_LINES + (size_t)(b * NLINES + rank) * 4) = ln;
            out[OFF_SCORE + b * NLINES + rank] = score;
        }
    }
}

// Serial keep test on stored lcmap (cold fallback path only).
__device__ bool keep_at(const float* __restrict__ L, int p) {
    int y = p >> 7, x = p & (WIDTH - 1);
    float v = L[p];
    for (int dy = -1; dy <= 1; ++dy) {
        int yy = y + dy;
        if (yy < 0 || yy >= WIDTH) continue;
        for (int dx = -1; dx <= 1; ++dx) {
            if (dy == 0 && dx == 0) continue;
            int xx = x + dx;
            if (xx < 0 || xx >= WIDTH) continue;
            if (L[yy * WIDTH + xx] > v) return false;
        }
    }
    return true;
}

// K4: never-triggering fallback: if cnt < 1000, top_k pads with zeros at the
// lowest non-kept flat indices; fill those slots (score 0, real endpoints).
__global__ void fb_fill_kernel(float* __restrict__ out, const int* __restrict__ wscnt) {
    const int b = blockIdx.x;
    int cnt = wscnt[b]; if (cnt > NCAND) cnt = NCAND;
    if (cnt >= NLINES) return;
    if (threadIdx.x != 0) return;
    const float* L = out + OFF_LCMAP + b * HW;
    const float* off0 = out + OFF_LCOFF + b * 2 * HW;
    const float* off1 = off0 + HW;
    const float* leng = out + OFF_LLENG + b * HW;
    const float* ang  = out + OFF_ANGLE + b * HW;
    int rank = cnt;
    for (int p = 0; p < HW && rank < NLINES; ++p) {
        if (keep_at(L, p)) continue;
        int yi = p >> 7, xi = p & (WIDTH - 1);
        float yc = (float)yi + off0[p] + 0.5f;
        float xc = (float)xi + off1[p] + 0.5f;
        float hl = leng[p] * 64.0f;
        float th = ang[p] * PI_F;
        float dy = hl * sinf(th);
        float dx = hl * cosf(th);
        float* lo = out + OFF_LINES + (size_t)(b * NLINES + rank) * 4;
        lo[0] = yc - dy; lo[1] = xc - dx; lo[2] = yc + dy; lo[3] = xc + dx;
        out[OFF_SCORE + b * NLINES + rank] = 0.0f;
        ++rank;
    }
}

// K5: structure NMS. Grid (16 k-tiles, 32 batches); block = 64 k x 4 i-splits.
// Uniform i-loop -> LDS broadcast reads; no early break (work is balanced).
// __f*_rn intrinsics forbid fma contraction so dist matches reference rounding.
__global__ __launch_bounds__(256) void nms_kernel(float* __restrict__ out) {
    __shared__ float4 lsv[NLINES];               // 16 KB (p1y,p1x,p2y,p2x)
    __shared__ unsigned char flags[64][NCHUNK];
    const int tile = blockIdx.x, b = blockIdx.y;
    const float4* lg = (const float4*)(out + OFF_LINES + (size_t)b * NLINES * 4);
    for (int i = threadIdx.x; i < NLINES; i += 256) lsv[i] = lg[i];
    __syncthreads();

    const int s  = threadIdx.x >> 6;             // i-range split 0..3
    const int kl = threadIdx.x & 63;
    const int k  = tile * 64 + kl;
    float4 P = lsv[k < NLINES ? k : 0];

    int istart = s * 250;
    int iend = min(250 * (s + 1), min(k, NLINES));
    bool sup = false;
    for (int i = istart; i < iend; ++i) {
        float4 Q = lsv[i];
        // d1 = |Q.p1-P.p1|^2 + |Q.p2-P.p2|^2  (reference association)
        float a1 = __fadd_rn(__fmul_rn(Q.x - P.x, Q.x - P.x),
                             __fmul_rn(Q.y - P.y, Q.y - P.y));
        float a2 = __fadd_rn(__fmul_rn(Q.z - P.z, Q.z - P.z),
                             __fmul_rn(Q.w - P.w, Q.w - P.w));
        float d1 = __fadd_rn(a1, a2);
        // d2 = |Q.p1-P.p2|^2 + |Q.p2-P.p1|^2
        float b1 = __fadd_rn(__fmul_rn(Q.x - P.z, Q.x - P.z),
                             __fmul_rn(Q.y - P.w, Q.y - P.w));
        float b2 = __fadd_rn(__fmul_rn(Q.z - P.x, Q.z - P.x),
                             __fmul_rn(Q.w - P.y, Q.w - P.y));
        float d2 = __fadd_rn(b1, b2);
        sup |= (fminf(d1, d2) <= 2.0f);
    }
    flags[kl][s] = (unsigned char)sup;
    __syncthreads();

    if (s == 0 && k < NLINES) {
        bool any = flags[kl][0] | flags[kl][1] | flags[kl][2] | flags[kl][3];
        float sc = out[OFF_SCORE + b * NLINES + k];
        out[OFF_SCORE + b * NLINES + k] = any ? 0.0f : sc;
    }
}

extern "C" void kernel_launch(void* const* d_in, const int* in_sizes, int n_in,
                              void* d_out, int out_size, void* d_ws, size_t ws_size,
                              hipStream_t stream) {
    const float* in = (const float*)d_in[0];
    float* out = (float*)d_out;
    (void)in_sizes; (void)n_in; (void)out_size;

    if (d_ws == nullptr || ws_size < WS_NEEDED) return;  // R2 confirmed ws >= 1MB
    int* wscnt = (int*)d_ws;
    unsigned long long* wskeys = (unsigned long long*)((char*)d_ws + WS_KEYS_OFF);

    zero_cnt_kernel<<<1, 64, 0, stream>>>(wscnt);
    prep_collect_kernel<<<(BATCH * HW) / 256, 256, 0, stream>>>(in, out, wskeys, wscnt);
    sort_chunks_kernel<<<dim3(NCHUNK, BATCH), 512, 0, stream>>>(wskeys, wscnt);
    merge_lines_kernel<<<BATCH, 1024, 0, stream>>>(out, wskeys);
    fb_fill_kernel<<<BATCH, 64, 0, stream>>>(out, wscnt);
    nms_kernel<<<dim3(16, BATCH), 256, 0, stream>>>(out);
}

// Round 4
// 63.519 us; speedup vs baseline: 4.0722x; 2.1623x over previous
//
#include <hip/hip_runtime.h>
#include <math.h>

#define BATCH 32
#define HW 16384
#define WIDTH 128
#define NLINES 1000
#define NCAND 4096
#define CHUNK 1024
#define NCHUNK 4
#define SLOTS_PER_BLOCK 64   // hard bound: max local maxima in a 2x128 tile

// Flat output offsets (float elements), reference return order:
// lcmap (32,128,128), lcoff (32,2,128,128), lleng (32,128,128),
// angle (32,128,128), lines (32,1000,2,2), score (32,1000)
#define OFF_LCMAP 0
#define OFF_LCOFF (BATCH * HW)
#define OFF_LLENG (OFF_LCOFF + 2 * BATCH * HW)
#define OFF_ANGLE (OFF_LLENG + BATCH * HW)
#define OFF_LINES (OFF_ANGLE + BATCH * HW)
#define OFF_SCORE (OFF_LINES + BATCH * NLINES * 4)

// Workspace: 32 batches x 4096 u64 keys (no counters, no atomics).
#define WS_NEEDED ((size_t)BATCH * NCAND * 8)

#define PI_F 3.14159265358979323846f

__device__ __forceinline__ float sigmoidf_(float x) {
    return 1.0f / (1.0f + expf(-x));
}

// Exactly the reference softmax([x0,x1])[1] op sequence -> bit-identical.
__device__ __forceinline__ float softmax1(float x0, float x1) {
    float m = fmaxf(x0, x1);
    float e0 = expf(x0 - m);
    float e1 = expf(x1 - m);
    return e1 / (e0 + e1);
}

__device__ __forceinline__ unsigned long long pack_key(float v, unsigned p) {
    // v > 0 -> float-bit order == value order; inverted index replicates
    // stable lax.top_k tie-breaking (lower index first). Never 0 for a real
    // candidate (low word = ~p != 0), so 0 marks an empty slot.
    return ((unsigned long long)__float_as_uint(v) << 32)
         | (unsigned long long)(0xFFFFFFFFu - p);
}

// K1: elementwise transforms + fused local-max collection, ATOMIC-FREE.
// Block = 256 threads = 2 rows of one batch; fixed 64-slot output region per
// block, slot assignment via block-local LDS prefix; unused slots zeroed.
__global__ __launch_bounds__(256) void prep_collect_kernel(
        const float* __restrict__ in, float* __restrict__ out,
        unsigned long long* __restrict__ wskeys) {
    __shared__ int wcnt_s[4];
    __shared__ int wpre_s[4];
    __shared__ int tot_s;

    int tid = blockIdx.x * 256 + threadIdx.x;
    int b = tid >> 14;              // HW = 16384
    int p = tid & (HW - 1);
    const float* __restrict__ ib = in + (size_t)b * 6 * HW;

    float x0 = ib[p];
    float x1 = ib[HW + p];
    float x2 = ib[2 * HW + p];
    float x3 = ib[3 * HW + p];
    float x4 = ib[4 * HW + p];
    float x5 = ib[5 * HW + p];

    float v = softmax1(x0, x1);
    out[OFF_LCMAP + tid] = v;
    out[OFF_LCOFF + b * 2 * HW + p]      = sigmoidf_(x2) - 0.5f;
    out[OFF_LCOFF + b * 2 * HW + HW + p] = sigmoidf_(x3) - 0.5f;
    out[OFF_LLENG + tid] = sigmoidf_(x4);
    out[OFF_ANGLE + tid] = sigmoidf_(x5);

    // 3x3 local-max test vs in-bounds neighbors (== h == maxpool3x3(h)).
    // Neighbor lcmap recomputed from input: bit-identical to stored values.
    int y = p >> 7, x = p & (WIDTH - 1);
    float m = -INFINITY;
    #pragma unroll
    for (int dy = -1; dy <= 1; ++dy) {
        #pragma unroll
        for (int dx = -1; dx <= 1; ++dx) {
            if (dy == 0 && dx == 0) continue;
            int yy = y + dy, xx = x + dx;
            int yc = min(max(yy, 0), WIDTH - 1);
            int xc = min(max(xx, 0), WIDTH - 1);
            int np = yc * WIDTH + xc;
            float nv = softmax1(ib[np], ib[HW + np]);
            bool inb = ((unsigned)yy < (unsigned)WIDTH) & ((unsigned)xx < (unsigned)WIDTH);
            m = fmaxf(m, inb ? nv : -INFINITY);
        }
    }
    bool keep = (v >= m);

    // Block-local compaction: wave popcounts -> exclusive prefix (thread 0).
    unsigned long long mask = __ballot(keep);
    int lane = threadIdx.x & 63;
    int w = threadIdx.x >> 6;
    if (lane == 0) wcnt_s[w] = __popcll(mask);
    __syncthreads();
    if (threadIdx.x == 0) {
        int a0 = wcnt_s[0], a1 = wcnt_s[1], a2 = wcnt_s[2], a3 = wcnt_s[3];
        wpre_s[0] = 0; wpre_s[1] = a0; wpre_s[2] = a0 + a1; wpre_s[3] = a0 + a1 + a2;
        tot_s = a0 + a1 + a2 + a3;
    }
    __syncthreads();

    unsigned long long* __restrict__ gk =
        wskeys + (size_t)b * NCAND + (size_t)(blockIdx.x & 63) * SLOTS_PER_BLOCK;
    if (keep) {
        int pos = wpre_s[w] + __popcll(mask & ((1ULL << lane) - 1ULL));
        if (pos < SLOTS_PER_BLOCK)           // unreachable for continuous data
            gk[pos] = pack_key(v, (unsigned)p);
    }
    int tot = tot_s < SLOTS_PER_BLOCK ? tot_s : SLOTS_PER_BLOCK;
    if (threadIdx.x < SLOTS_PER_BLOCK && threadIdx.x >= tot)
        gk[threadIdx.x] = 0ULL;              // zero-fill empty slots
}

// K2: per-(batch,chunk) bitonic sort of 1024 keys, descending.
__global__ __launch_bounds__(512) void sort_chunks_kernel(
        unsigned long long* __restrict__ wskeys) {
    __shared__ unsigned long long sk[CHUNK];
    const int c = blockIdx.x, b = blockIdx.y;
    const int base = c * CHUNK;
    unsigned long long* gk = wskeys + (size_t)b * NCAND;

    for (int i = threadIdx.x; i < CHUNK; i += 512) sk[i] = gk[base + i];
    __syncthreads();

    for (int size = 2; size <= CHUNK; size <<= 1) {
        for (int stride = size >> 1; stride > 0; stride >>= 1) {
            int t = threadIdx.x;
            int i = ((t & ~(stride - 1)) << 1) | (t & (stride - 1));
            int j = i | stride;
            bool asc = (i & size) != 0;
            unsigned long long a = sk[i], cc = sk[j];
            if ((a < cc) != asc) { sk[i] = cc; sk[j] = a; }
            __syncthreads();
        }
    }
    for (int i = threadIdx.x; i < CHUNK; i += 512) gk[base + i] = sk[i];
}

// K3: merge 4 sorted chunks by exact rank (binary search; nonzero keys are
// unique), compute line endpoints + raw scores for ranks < 1000.
__global__ __launch_bounds__(1024) void merge_lines_kernel(
        float* __restrict__ out, const unsigned long long* __restrict__ wskeys) {
    __shared__ unsigned long long sk[NCAND];   // 32 KB
    const int b = blockIdx.x;
    const unsigned long long* gk = wskeys + (size_t)b * NCAND;
    for (int i = threadIdx.x; i < NCAND; i += 1024) sk[i] = gk[i];
    __syncthreads();

    const float* off0 = out + OFF_LCOFF + b * 2 * HW;
    const float* off1 = off0 + HW;
    const float* leng = out + OFF_LLENG + b * HW;
    const float* ang  = out + OFF_ANGLE + b * HW;

    for (int mslot = threadIdx.x; mslot < NCAND; mslot += 1024) {
        unsigned long long e = sk[mslot];
        if (e == 0ULL) continue;                 // empty slot
        int c = mslot >> 10;
        int rank = mslot & (CHUNK - 1);          // local rank in own chunk
        #pragma unroll
        for (int c2 = 0; c2 < NCHUNK; ++c2) {
            if (c2 == c) continue;
            const unsigned long long* A = sk + c2 * CHUNK;
            int lo = 0, hi = CHUNK;
            while (lo < hi) {
                int mid = (lo + hi) >> 1;
                if (A[mid] > e) lo = mid + 1; else hi = mid;
            }
            rank += lo;                          // count of keys > e in c2
        }
        if (rank < NLINES) {
            unsigned p = 0xFFFFFFFFu - (unsigned)(e & 0xFFFFFFFFull);
            float score = __uint_as_float((unsigned)(e >> 32));
            int yi = (int)(p >> 7), xi = (int)(p & (WIDTH - 1));
            float yc = (float)yi + off0[p] + 0.5f;
            float xc = (float)xi + off1[p] + 0.5f;
            float hl = leng[p] * 64.0f;          // RESOLUTION/2
            float th = ang[p] * PI_F;
            float dy = hl * sinf(th);
            float dx = hl * cosf(th);
            float4 ln = make_float4(yc - dy, xc - dx, yc + dy, xc + dx);
            *(float4*)(out + OFF_LINES + (size_t)(b * NLINES + rank) * 4) = ln;
            out[OFF_SCORE + b * NLINES + rank] = score;
        }
    }
}

// Serial keep test on stored lcmap (cold fallback path only).
__device__ bool keep_at(const float* __restrict__ L, int p) {
    int y = p >> 7, x = p & (WIDTH - 1);
    float v = L[p];
    for (int dy = -1; dy <= 1; ++dy) {
        int yy = y + dy;
        if (yy < 0 || yy >= WIDTH) continue;
        for (int dx = -1; dx <= 1; ++dx) {
            if (dy == 0 && dx == 0) continue;
            int xx = x + dx;
            if (xx < 0 || xx >= WIDTH) continue;
            if (L[yy * WIDTH + xx] > v) return false;
        }
    }
    return true;
}

// K4: never-triggering fallback. Counts candidates from the key array; if
// cnt < 1000, top_k pads with zeros at the lowest non-kept flat indices.
__global__ __launch_bounds__(256) void fb_fill_kernel(
        float* __restrict__ out, const unsigned long long* __restrict__ wskeys) {
    __shared__ int wsum[4];
    __shared__ int cnt_s;
    const int b = blockIdx.x;
    const unsigned long long* gk = wskeys + (size_t)b * NCAND;
    int local = 0;
    for (int i = threadIdx.x; i < NCAND; i += 256) local += (gk[i] != 0ULL);
    for (int off = 32; off; off >>= 1) local += __shfl_down(local, off);
    if ((threadIdx.x & 63) == 0) wsum[threadIdx.x >> 6] = local;
    __syncthreads();
    if (threadIdx.x == 0) cnt_s = wsum[0] + wsum[1] + wsum[2] + wsum[3];
    __syncthreads();
    if (cnt_s >= NLINES) return;
    if (threadIdx.x != 0) return;

    const float* L = out + OFF_LCMAP + b * HW;
    const float* off0 = out + OFF_LCOFF + b * 2 * HW;
    const float* off1 = off0 + HW;
    const float* leng = out + OFF_LLENG + b * HW;
    const float* ang  = out + OFF_ANGLE + b * HW;
    int rank = cnt_s;
    for (int p = 0; p < HW && rank < NLINES; ++p) {
        if (keep_at(L, p)) continue;
        int yi = p >> 7, xi = p & (WIDTH - 1);
        float yc = (float)yi + off0[p] + 0.5f;
        float xc = (float)xi + off1[p] + 0.5f;
        float hl = leng[p] * 64.0f;
        float th = ang[p] * PI_F;
        float dy = hl * sinf(th);
        float dx = hl * cosf(th);
        float* lo = out + OFF_LINES + (size_t)(b * NLINES + rank) * 4;
        lo[0] = yc - dy; lo[1] = xc - dx; lo[2] = yc + dy; lo[3] = xc + dx;
        out[OFF_SCORE + b * NLINES + rank] = 0.0f;
        ++rank;
    }
}

// K5: structure NMS. Grid (16 k-tiles, 32 batches); block = 64 k x 4 i-splits.
// __f*_rn intrinsics forbid fma contraction so dist matches reference rounding.
__global__ __launch_bounds__(256) void nms_kernel(float* __restrict__ out) {
    __shared__ float4 lsv[NLINES];               // 16 KB
    __shared__ unsigned char flags[64][NCHUNK];
    const int tile = blockIdx.x, b = blockIdx.y;
    const float4* lg = (const float4*)(out + OFF_LINES + (size_t)b * NLINES * 4);
    for (int i = threadIdx.x; i < NLINES; i += 256) lsv[i] = lg[i];
    __syncthreads();

    const int s  = threadIdx.x >> 6;             // i-range split 0..3
    const int kl = threadIdx.x & 63;
    const int k  = tile * 64 + kl;
    float4 P = lsv[k < NLINES ? k : 0];

    int istart = s * 250;
    int iend = min(250 * (s + 1), min(k, NLINES));
    bool sup = false;
    for (int i = istart; i < iend; ++i) {
        float4 Q = lsv[i];
        float a1 = __fadd_rn(__fmul_rn(Q.x - P.x, Q.x - P.x),
                             __fmul_rn(Q.y - P.y, Q.y - P.y));
        float a2 = __fadd_rn(__fmul_rn(Q.z - P.z, Q.z - P.z),
                             __fmul_rn(Q.w - P.w, Q.w - P.w));
        float d1 = __fadd_rn(a1, a2);
        float b1 = __fadd_rn(__fmul_rn(Q.x - P.z, Q.x - P.z),
                             __fmul_rn(Q.y - P.w, Q.y - P.w));
        float b2 = __fadd_rn(__fmul_rn(Q.z - P.x, Q.z - P.x),
                             __fmul_rn(Q.w - P.y, Q.w - P.y));
        float d2 = __fadd_rn(b1, b2);
        sup |= (fminf(d1, d2) <= 2.0f);
    }
    flags[kl][s] = (unsigned char)sup;
    __syncthreads();

    if (s == 0 && k < NLINES) {
        bool any = flags[kl][0] | flags[kl][1] | flags[kl][2] | flags[kl][3];
        float sc = out[OFF_SCORE + b * NLINES + k];
        out[OFF_SCORE + b * NLINES + k] = any ? 0.0f : sc;
    }
}

extern "C" void kernel_launch(void* const* d_in, const int* in_sizes, int n_in,
                              void* d_out, int out_size, void* d_ws, size_t ws_size,
                              hipStream_t stream) {
    const float* in = (const float*)d_in[0];
    float* out = (float*)d_out;
    (void)in_sizes; (void)n_in; (void)out_size;

    if (d_ws == nullptr || ws_size < WS_NEEDED) return;  // ws >= 1MB confirmed
    unsigned long long* wskeys = (unsigned long long*)d_ws;

    prep_collect_kernel<<<(BATCH * HW) / 256, 256, 0, stream>>>(in, out, wskeys);
    sort_chunks_kernel<<<dim3(NCHUNK, BATCH), 512, 0, stream>>>(wskeys);
    merge_lines_kernel<<<BATCH, 1024, 0, stream>>>(out, wskeys);
    fb_fill_kernel<<<BATCH, 256, 0, stream>>>(out, wskeys);
    nms_kernel<<<dim3(16, BATCH), 256, 0, stream>>>(out);
}